// Round 2
// baseline (40749.240 us; speedup 1.0000x reference)
//
#include <hip/hip_runtime.h>
#include <stdint.h>
#include <stddef.h>

// MambaBlock on MI355X (gfx950).
// out = OutProj( scan_t( s_t = tanh(A(g_t*s_{t-1}) + v_t) ) )
// with v = ((1-g)*inp)@A^T + inp@B^T hoisted into one K=2048 GEMM.
//
// Round 4: HARDENED XCD-LOCAL SCAN (hang-proof).
//  - 256 candidate WGs; each reads its physical XCD (s_getreg XCC_ID builtin),
//    registers on a per-XCD counter; first XCD to 16 members CAS-claims the
//    team (pigeonhole: 256 WGs over <=16 buckets guarantees a winner).
//  - TWO-phase coherence probe among the 16 winners: phase 1 checks cross-CU
//    sc0 visibility, phase 2 RE-READS the same addresses after an update
//    (catches "sc0 load served stale from L1" -- the infinite-poll hang mode).
//    Verdict is unanimous (seq_cst fail word + acquire rendezvous).
//  - FAST scan body uses sc0-only (XCD-L2 coherence point, ~200cy hops vs
//    ~1.4us LLC hops). Every poll also reads a poison word; any wave stalled
//    > 8192 poll iters sets poison. On poison a wave re-publishes BOTH parity
//    slots of its m region + its flag to the LLC (max skew = 1 step, so the
//    slots hold exactly {m_t, m_{t-1}}) and switches to the LLC body, which
//    dual-stores (sc0 + sc0 sc1) so stragglers converge. No unbounded spin
//    depends on unverified semantics -> cannot hang; worst case ~= baseline.

#define DIM   1024
#define SEQ   4096
#define NB    8
#define NTOK  (NB*SEQ)   // 32768

typedef __attribute__((ext_vector_type(8))) short          short8;
typedef __attribute__((ext_vector_type(4))) float          float4v;
typedef __attribute__((ext_vector_type(4))) int            int4v;
typedef __attribute__((ext_vector_type(4))) unsigned short ushort4v;

__device__ __forceinline__ unsigned short f2b(float f) {
  union { float f; unsigned int u; } v; v.f = f;
  return (unsigned short)((v.u + 0x7FFFu + ((v.u >> 16) & 1u)) >> 16);   // RNE
}
__device__ __forceinline__ float b2f(unsigned short h) {
  union { unsigned int u; float f; } v; v.u = ((unsigned int)h) << 16;
  return v.f;
}

// ---------------------------------------------------------------- small prep
__global__ void cast_bf16(const float* __restrict__ src,
                          unsigned short* __restrict__ dst, int n) {
  int i4 = (blockIdx.x * blockDim.x + threadIdx.x) * 4;
  if (i4 >= n) return;
  float4v v = *(const float4v*)(src + i4);
  ushort4v o;
  o[0] = f2b(v[0]); o[1] = f2b(v[1]); o[2] = f2b(v[2]); o[3] = f2b(v[3]);
  *(ushort4v*)(dst + i4) = o;
}

// Wcat[e][0:1024] = B[e][:], Wcat[e][1024:2048] = A[e][:]; Ab = bf16(A)
__global__ void build_wcat(const float* __restrict__ Bm, const float* __restrict__ A,
                           unsigned short* __restrict__ Wcat,
                           unsigned short* __restrict__ Ab) {
  int i4 = (blockIdx.x * 256 + threadIdx.x) * 4;       // 0..1048572
  int e = i4 >> 10, d = i4 & 1023;
  float4v bv = *(const float4v*)(Bm + i4);
  float4v av = *(const float4v*)(A + i4);
  ushort4v bb, ab;
  #pragma unroll
  for (int r = 0; r < 4; r++) { bb[r] = f2b(bv[r]); ab[r] = f2b(av[r]); }
  *(ushort4v*)(Wcat + (size_t)e * 2048 + d) = bb;
  *(ushort4v*)(Wcat + (size_t)e * 2048 + 1024 + d) = ab;
  *(ushort4v*)(Ab + i4) = ab;
}

// zero mbuf+flags+ctl; ctl.winner (global u32 index widx) = -1
__global__ void init_ws(unsigned int* __restrict__ p, int n, int widx) {
  int i = blockIdx.x * 256 + threadIdx.x;
  if (i < n) p[i] = (i == widx) ? 0xFFFFFFFFu : 0u;
}

// ---------------------------------------------------------------- GEMM (NT)
// C[m,n] = sum_k Ag[m,k]*Bg[n,k]  (both K-contiguous), 128x128 tile, BK=64.
// LDS rows padded to 72 elems -> conflict-free b128.
// EPI: 0 inp->inpq[:, :1024] bf16 | 1 gate->gscan bf16 + q->inpq[:,1024:]
//      2 v->fp32 [t*8+b][e]       | 3 out->fp32 [b*4096+t][e]
template<int EPI>
__global__ __launch_bounds__(256, 2)
void gemm_nt(const unsigned short* __restrict__ Ag, int lda,
             const unsigned short* __restrict__ Bg, int ldb,
             int K,
             const float* __restrict__ bias,
             void* __restrict__ out0,
             unsigned short* __restrict__ out1,
             const unsigned short* __restrict__ aux) {
  __shared__ unsigned short sA[128 * 72];
  __shared__ unsigned short sB[128 * 72];
  const int tid  = threadIdx.x;
  const int lane = tid & 63;
  const int wave = tid >> 6;
  const int wm = wave & 1, wn = wave >> 1;
  const int m0 = blockIdx.x * 128;
  const int n0 = blockIdx.y * 128;
  const int q  = lane >> 4;
  const int ln = lane & 15;

  float4v acc[4][4];
  const float4v fz = {0.f, 0.f, 0.f, 0.f};
  #pragma unroll
  for (int i = 0; i < 4; i++)
    #pragma unroll
    for (int j = 0; j < 4; j++) acc[i][j] = fz;

  for (int kk = 0; kk < K; kk += 64) {
    __syncthreads();                       // protect LDS reuse
    #pragma unroll
    for (int s = 0; s < 4; s++) {          // stage 128x64 of A and B
      int chunk = tid + s * 256;           // 0..1023 : row*8 + c
      int row = chunk >> 3, c = chunk & 7;
      int4v va = *(const int4v*)(Ag + (size_t)(m0 + row) * lda + kk + c * 8);
      int4v vb = *(const int4v*)(Bg + (size_t)(n0 + row) * ldb + kk + c * 8);
      *(int4v*)(sA + row * 72 + c * 8) = va;
      *(int4v*)(sB + row * 72 + c * 8) = vb;
    }
    __syncthreads();
    #pragma unroll
    for (int ks = 0; ks < 64; ks += 32) {
      short8 af[4], bf[4];
      #pragma unroll
      for (int i = 0; i < 4; i++)
        af[i] = *(const short8*)(sA + (wm * 64 + i * 16 + ln) * 72 + ks + q * 8);
      #pragma unroll
      for (int j = 0; j < 4; j++)
        bf[j] = *(const short8*)(sB + (wn * 64 + j * 16 + ln) * 72 + ks + q * 8);
      #pragma unroll
      for (int i = 0; i < 4; i++)
        #pragma unroll
        for (int j = 0; j < 4; j++)
          acc[i][j] = __builtin_amdgcn_mfma_f32_16x16x32_bf16(af[i], bf[j], acc[i][j], 0, 0, 0);
    }
  }

  #pragma unroll
  for (int j = 0; j < 4; j++) {
    const int gn = n0 + wn * 64 + j * 16 + ln;      // N index (feature e)
    const float bval = (EPI == 2) ? 0.f : bias[gn];
    #pragma unroll
    for (int i = 0; i < 4; i++) {
      const int gm = m0 + wm * 64 + i * 16 + q * 4; // M index (token row)
      #pragma unroll
      for (int r = 0; r < 4; r++) {
        const int row = gm + r;
        float vv = acc[i][j][r] + bval;
        if constexpr (EPI == 0) {
          ((unsigned short*)out0)[(size_t)row * 2048 + gn] = f2b(vv);
        } else if constexpr (EPI == 1) {
          float g = 1.f / (1.f + __expf(-vv));
          int t = row & (SEQ - 1), b = row >> 12;   // token row = b*SEQ + t
          ((unsigned short*)out0)[(size_t)(t * NB + b) * DIM + gn] = f2b(g);
          float iv = b2f(aux[(size_t)row * 2048 + gn]);
          out1[(size_t)row * 2048 + 1024 + gn] = f2b((1.f - g) * iv);
        } else if constexpr (EPI == 2) {
          int t = row & (SEQ - 1), b = row >> 12;
          ((float*)out0)[(size_t)(t * NB + b) * DIM + gn] = vv;
        } else {                                    // row = t*8 + b
          int b = row & 7, t = row >> 3;
          ((float*)out0)[(size_t)(b * SEQ + t) * DIM + gn] = vv;
        }
      }
    }
  }
}

// ---------------------------------------------------------------- scan: LLC body
// Proven round-0 protocol (sc0 sc1 = LLC coherence point), from step t0.
// Stores are DUAL (sc0 then sc0 sc1) so any straggler still in fast mode keeps
// seeing progress through the XCD L2 while it converges onto this path.
__device__ void scan_llc(const int t0, const int gw, const int lane,
                         const unsigned short* __restrict__ Ab,
                         const unsigned short* __restrict__ gscan,
                         const float* __restrict__ vflat,
                         unsigned short* __restrict__ sb,
                         unsigned short* __restrict__ mbuf,
                         unsigned int* __restrict__ flags) {
  const int e0  = gw * 16;
  const int q   = lane >> 4;
  const int ln  = lane & 15;
  const int bcl = ln & 7;
  const bool active = (ln < 8);
  const int eb = e0 + q * 4;

  short8 af[32];                             // A rows in registers
  #pragma unroll
  for (int ks = 0; ks < 32; ks++)
    af[ks] = *(const short8*)(Ab + (size_t)(e0 + ln) * 1024 + ks * 32 + q * 8);

  const unsigned int* fpoll = flags + lane;
  unsigned int* const myflag = flags + gw;
  const float4v fz = {0.f, 0.f, 0.f, 0.f};

  for (int t = t0; t < SEQ; t++) {
    float4v vv = fz;
    ushort4v g4 = {0, 0, 0, 0};
    size_t rowoff = (size_t)(t * NB + bcl) * DIM + eb;
    if (active) {
      vv = *(const float4v*)(vflat + rowoff);
      if (t < SEQ - 1)
        g4 = *(const ushort4v*)(gscan + (size_t)((t + 1) * NB + bcl) * DIM + eb);
    }

    {
      const unsigned int target = (unsigned int)t;
      for (;;) {
        unsigned int pv;
        asm volatile("global_load_dword %0, %1, off sc0 sc1\n\t"
                     "s_waitcnt vmcnt(0)"
                     : "=v"(pv) : "v"(fpoll) : "memory");
        if (__all((int)(pv >= target))) break;
      }
    }

    const unsigned short* mb = mbuf + (size_t)(t & 1) * (NB * DIM);
    const unsigned short* mbp = mb + bcl * DIM + q * 8;
    short8 fr[32];
    #pragma unroll
    for (int ks = 0; ks < 32; ks++)
      asm volatile("global_load_dwordx4 %0, %1, off offset:%2 sc0 sc1"
                   : "=v"(fr[ks]) : "v"(mbp), "n"(ks * 64));

    float4v a0 = fz, a1 = fz, a2 = fz, a3 = fz;
    #pragma unroll
    for (int c = 0; c < 8; c++) {
      asm volatile("s_waitcnt vmcnt(%4)"
                   : "+v"(fr[4 * c]), "+v"(fr[4 * c + 1]),
                     "+v"(fr[4 * c + 2]), "+v"(fr[4 * c + 3])
                   : "n"(28 - 4 * c));
      a0 = __builtin_amdgcn_mfma_f32_16x16x32_bf16(af[4 * c + 0], fr[4 * c + 0], a0, 0, 0, 0);
      a1 = __builtin_amdgcn_mfma_f32_16x16x32_bf16(af[4 * c + 1], fr[4 * c + 1], a1, 0, 0, 0);
      a2 = __builtin_amdgcn_mfma_f32_16x16x32_bf16(af[4 * c + 2], fr[4 * c + 2], a2, 0, 0, 0);
      a3 = __builtin_amdgcn_mfma_f32_16x16x32_bf16(af[4 * c + 3], fr[4 * c + 3], a3, 0, 0, 0);
    }

    if (active) {
      float sv[4];
      #pragma unroll
      for (int r = 0; r < 4; r++) {
        float xx = a0[r] + a1[r] + a2[r] + a3[r] + vv[r];
        float ex = __expf(-2.f * fabsf(xx));
        float th = (1.f - ex) / (1.f + ex);
        sv[r] = copysignf(th, xx);
      }
      ushort4v sp;
      #pragma unroll
      for (int r = 0; r < 4; r++) sp[r] = f2b(sv[r]);
      *(ushort4v*)(sb + rowoff) = sp;                       // state for out-proj
      if (t < SEQ - 1) {                                    // m_{t+1} = g*s
        unsigned long long mv =
            (unsigned long long)((unsigned int)f2b(b2f(g4[0]) * sv[0]) |
                                 ((unsigned int)f2b(b2f(g4[1]) * sv[1]) << 16)) |
            ((unsigned long long)((unsigned int)f2b(b2f(g4[2]) * sv[2]) |
                                  ((unsigned int)f2b(b2f(g4[3]) * sv[3]) << 16)) << 32);
        unsigned short* mn = mbuf + (size_t)((t + 1) & 1) * (NB * DIM) + bcl * DIM + eb;
        asm volatile("global_store_dwordx2 %0, %1, off sc0"
                     :: "v"(mn), "v"(mv) : "memory");
        asm volatile("global_store_dwordx2 %0, %1, off sc0 sc1"
                     :: "v"(mn), "v"(mv) : "memory");
      }
    }

    if (t == SEQ - 1) break;

    asm volatile("s_waitcnt vmcnt(0)" ::: "memory");
    if (lane == 0) {
      unsigned int fv = (unsigned int)(t + 1);
      asm volatile("global_store_dword %0, %1, off sc0"
                   :: "v"(myflag), "v"(fv) : "memory");
      asm volatile("global_store_dword %0, %1, off sc0 sc1"
                   :: "v"(myflag), "v"(fv) : "memory");
    }
  }
}

// ---------------------------------------------------------------- scan: fast body
// sc0-only (XCD-L2 coherence point). Bounded polls; on poison/timeout,
// re-publish both parity m-slots + own flag at LLC and return the step to
// resume in scan_llc. Returns SEQ when the whole scan completed fast.
__device__ int scan_fast(const int gw, const int lane,
                         const unsigned short* __restrict__ Ab,
                         const unsigned short* __restrict__ gscan,
                         const float* __restrict__ vflat,
                         unsigned short* __restrict__ sb,
                         unsigned short* __restrict__ mbuf,
                         unsigned int* __restrict__ flags,
                         unsigned int* __restrict__ poisonw) {
  const int e0  = gw * 16;
  const int q   = lane >> 4;
  const int ln  = lane & 15;
  const int bcl = ln & 7;
  const bool active = (ln < 8);
  const int eb = e0 + q * 4;

  short8 af[32];
  #pragma unroll
  for (int ks = 0; ks < 32; ks++)
    af[ks] = *(const short8*)(Ab + (size_t)(e0 + ln) * 1024 + ks * 32 + q * 8);

  const unsigned int* fpoll = flags + lane;
  unsigned int* const myflag = flags + gw;
  const float4v fz = {0.f, 0.f, 0.f, 0.f};

  for (int t = 0; t < SEQ; t++) {
    float4v vv = fz;
    ushort4v g4 = {0, 0, 0, 0};
    size_t rowoff = (size_t)(t * NB + bcl) * DIM + eb;
    if (active) {
      vv = *(const float4v*)(vflat + rowoff);
      if (t < SEQ - 1)
        g4 = *(const ushort4v*)(gscan + (size_t)((t + 1) * NB + bcl) * DIM + eb);
    }

    // ---- bounded poll: flags[lane] >= t, plus poison word, all via sc0 (L2)
    const unsigned int target = (unsigned int)t;
    bool bail = false;
    {
      unsigned int iters = 0;
      for (;;) {
        unsigned int pv, po;
        asm volatile("global_load_dword %0, %2, off sc0\n\t"
                     "global_load_dword %1, %3, off sc0\n\t"
                     "s_waitcnt vmcnt(0)"
                     : "=&v"(pv), "=&v"(po)
                     : "v"(fpoll), "v"(poisonw) : "memory");
        if (__all((int)(pv >= target))) break;
        if (po != 0u) { bail = true; break; }
        if (++iters >= 8192u) {                  // ~1ms of stall -> poison
          if (lane == 0) {
            unsigned int one = 1u;
            asm volatile("global_store_dword %0, %1, off sc0"
                         :: "v"(poisonw), "v"(one) : "memory");
            asm volatile("global_store_dword %0, %1, off sc0 sc1"
                         :: "v"(poisonw), "v"(one) : "memory");
          }
          bail = true; break;
        }
      }
    }
    if (bail) {
      // re-publish BOTH parity slots of own m (they hold {m_t, m_{t-1}};
      // max barrier skew is 1 step so that covers every possible reader),
      // then own flag (= t), all at LLC scope. Resume in scan_llc(t).
      if (active) {
        #pragma unroll
        for (int par = 0; par < 2; par++) {
          unsigned short* mp = mbuf + (size_t)par * (NB * DIM) + bcl * DIM + eb;
          unsigned long long mv_;
          asm volatile("global_load_dwordx2 %0, %1, off sc0\n\t"
                       "s_waitcnt vmcnt(0)"
                       : "=&v"(mv_) : "v"(mp) : "memory");
          asm volatile("global_store_dwordx2 %0, %1, off sc0 sc1"
                       :: "v"(mp), "v"(mv_) : "memory");
        }
      }
      asm volatile("s_waitcnt vmcnt(0)" ::: "memory");
      if (lane == 0)
        asm volatile("global_store_dword %0, %1, off sc0 sc1"
                     :: "v"(myflag), "v"(target) : "memory");
      return t;
    }

    // ---- m_t fragments from the XCD L2 (sc0), active lanes only
    const unsigned short* mb = mbuf + (size_t)(t & 1) * (NB * DIM);
    const unsigned short* mbp = mb + bcl * DIM + q * 8;
    short8 fr[32];
    if (active) {
      #pragma unroll
      for (int ks = 0; ks < 32; ks++)
        asm volatile("global_load_dwordx4 %0, %1, off offset:%2 sc0"
                     : "=v"(fr[ks]) : "v"(mbp), "n"(ks * 64));
    }

    float4v a0 = fz, a1 = fz, a2 = fz, a3 = fz;
    #pragma unroll
    for (int c = 0; c < 8; c++) {
      asm volatile("s_waitcnt vmcnt(%4)"
                   : "+v"(fr[4 * c]), "+v"(fr[4 * c + 1]),
                     "+v"(fr[4 * c + 2]), "+v"(fr[4 * c + 3])
                   : "n"(28 - 4 * c));
      a0 = __builtin_amdgcn_mfma_f32_16x16x32_bf16(af[4 * c + 0], fr[4 * c + 0], a0, 0, 0, 0);
      a1 = __builtin_amdgcn_mfma_f32_16x16x32_bf16(af[4 * c + 1], fr[4 * c + 1], a1, 0, 0, 0);
      a2 = __builtin_amdgcn_mfma_f32_16x16x32_bf16(af[4 * c + 2], fr[4 * c + 2], a2, 0, 0, 0);
      a3 = __builtin_amdgcn_mfma_f32_16x16x32_bf16(af[4 * c + 3], fr[4 * c + 3], a3, 0, 0, 0);
    }

    if (active) {
      float sv[4];
      #pragma unroll
      for (int r = 0; r < 4; r++) {
        float xx = a0[r] + a1[r] + a2[r] + a3[r] + vv[r];
        float ex = __expf(-2.f * fabsf(xx));
        float th = (1.f - ex) / (1.f + ex);
        sv[r] = copysignf(th, xx);
      }
      ushort4v sp;
      #pragma unroll
      for (int r = 0; r < 4; r++) sp[r] = f2b(sv[r]);
      *(ushort4v*)(sb + rowoff) = sp;
      if (t < SEQ - 1) {
        unsigned long long mv =
            (unsigned long long)((unsigned int)f2b(b2f(g4[0]) * sv[0]) |
                                 ((unsigned int)f2b(b2f(g4[1]) * sv[1]) << 16)) |
            ((unsigned long long)((unsigned int)f2b(b2f(g4[2]) * sv[2]) |
                                  ((unsigned int)f2b(b2f(g4[3]) * sv[3]) << 16)) << 32);
        unsigned short* mn = mbuf + (size_t)((t + 1) & 1) * (NB * DIM) + bcl * DIM + eb;
        asm volatile("global_store_dwordx2 %0, %1, off sc0"
                     :: "v"(mn), "v"(mv) : "memory");
      }
    }

    if (t == SEQ - 1) break;

    asm volatile("s_waitcnt vmcnt(0)" ::: "memory");   // m landed in L2
    if (lane == 0) {
      unsigned int fv = (unsigned int)(t + 1);
      asm volatile("global_store_dword %0, %1, off sc0"
                   :: "v"(myflag), "v"(fv) : "memory");
    }
  }
  return SEQ;
}

// ---------------------------------------------------------------- scan kernel
// ctl layout (u32): [0:16) per-XCD counters | 16 winner(-1) | 17 ready1 |
// [18:34) probe sigs | 34 ready2 | 35 ready3 | 36 fail | 40 poison
__global__ __launch_bounds__(256, 1)
void scan_kernel(const unsigned short* __restrict__ Ab,     // [1024][1024] bf16
                 const unsigned short* __restrict__ gscan,  // [t*8+b][1024] bf16
                 const float* __restrict__ vflat,           // [t*8+b][1024] f32
                 unsigned short* __restrict__ sb,           // [t*8+b][1024] bf16
                 unsigned short* __restrict__ mbuf,         // [2][8][1024] bf16
                 unsigned int* __restrict__ flags,          // [64]
                 unsigned int* __restrict__ ctl) {
  const int tid  = threadIdx.x;
  const int lane = tid & 63;
  const int wave = tid >> 6;

  __shared__ int s_rank, s_mode;
  if (tid == 0) {
    // ---- election: first XCD to 16 registered WGs claims the team
    unsigned int xcd = __builtin_amdgcn_s_getreg(63508) & 15u;  // id20,off0,sz32 = XCC_ID
    int* winner = (int*)(ctl + 16);
    unsigned int r = __hip_atomic_fetch_add(&ctl[xcd], 1u,
                        __ATOMIC_RELAXED, __HIP_MEMORY_SCOPE_AGENT);
    if (r == 15u) {
      int expected = -1;
      __hip_atomic_compare_exchange_strong(winner, &expected, (int)xcd,
          __ATOMIC_RELAXED, __ATOMIC_RELAXED, __HIP_MEMORY_SCOPE_AGENT);
    }
    int w;
    for (;;) {                              // winner guaranteed (pigeonhole)
      w = __hip_atomic_load(winner, __ATOMIC_RELAXED, __HIP_MEMORY_SCOPE_AGENT);
      if (w != -1) break;
      __builtin_amdgcn_s_sleep(8);
    }
    int rank = (r < 16u && (int)xcd == w) ? (int)r : -1;

    // ---- two-phase coherence probe (winners only), unanimous verdict
    int mode = 1;
    if (rank >= 0) {
      unsigned int* sig    = ctl + 18;
      unsigned int* ready1 = ctl + 17;
      unsigned int* ready2 = ctl + 34;
      unsigned int* ready3 = ctl + 35;
      unsigned int* fail   = ctl + 36;
      int ok = 1;
      const unsigned int pats[2] = {0xC0DE0000u, 0xFEED0000u};
      unsigned int* readys[2] = {ready1, ready2};
      for (int ph = 0; ph < 2; ph++) {
        unsigned int pat = pats[ph] | (unsigned int)rank;
        const unsigned int* pw = sig + rank;
        asm volatile("global_store_dword %0, %1, off sc0\n\t"
                     "s_waitcnt vmcnt(0)"
                     :: "v"(pw), "v"(pat) : "memory");
        __hip_atomic_fetch_add(readys[ph], 1u,
            __ATOMIC_SEQ_CST, __HIP_MEMORY_SCOPE_AGENT);
        while (__hip_atomic_load(readys[ph],
                 __ATOMIC_ACQUIRE, __HIP_MEMORY_SCOPE_AGENT) < 16u)
          __builtin_amdgcn_s_sleep(2);
        for (int i = 0; i < 16; i++) {
          unsigned int v;
          const unsigned int* pp = sig + i;
          asm volatile("global_load_dword %0, %1, off sc0\n\t"
                       "s_waitcnt vmcnt(0)"
                       : "=&v"(v) : "v"(pp) : "memory");
          if (v != (pats[ph] | (unsigned int)i)) ok = 0;   // stale -> not one L2
        }
      }
      if (!ok)
        __hip_atomic_fetch_add(fail, 1u, __ATOMIC_SEQ_CST, __HIP_MEMORY_SCOPE_AGENT);
      __hip_atomic_fetch_add(ready3, 1u, __ATOMIC_SEQ_CST, __HIP_MEMORY_SCOPE_AGENT);
      while (__hip_atomic_load(ready3,
               __ATOMIC_ACQUIRE, __HIP_MEMORY_SCOPE_AGENT) < 16u)
        __builtin_amdgcn_s_sleep(2);
      mode = (__hip_atomic_load(fail,
               __ATOMIC_ACQUIRE, __HIP_MEMORY_SCOPE_AGENT) != 0u) ? 1 : 0;
    }
    s_rank = rank;
    s_mode = mode;
  }
  __syncthreads();
  const int rank = s_rank;
  if (rank < 0) return;                     // losing WGs exit
  const int gw = rank * 4 + wave;           // 0..63

  if (s_mode == 0) {
    int tr = scan_fast(gw, lane, Ab, gscan, vflat, sb, mbuf, flags, ctl + 40);
    if (tr < SEQ)
      scan_llc(tr, gw, lane, Ab, gscan, vflat, sb, mbuf, flags);
  } else {
    scan_llc(0, gw, lane, Ab, gscan, vflat, sb, mbuf, flags);
  }
}

// ---------------------------------------------------------------- launch
extern "C" void kernel_launch(void* const* d_in, const int* in_sizes, int n_in,
                              void* d_out, int out_size, void* d_ws, size_t ws_size,
                              hipStream_t stream) {
  const float* x      = (const float*)d_in[0];
  const float* A      = (const float*)d_in[1];
  const float* Bm     = (const float*)d_in[2];
  const float* W_in   = (const float*)d_in[3];
  const float* b_in   = (const float*)d_in[4];
  const float* W_gate = (const float*)d_in[5];
  const float* b_gate = (const float*)d_in[6];
  const float* W_out  = (const float*)d_in[7];
  const float* b_out  = (const float*)d_in[8];

  char* ws = (char*)d_ws;
  // workspace layout (~281 MB total + ctl tail)
  unsigned short* xb      = (unsigned short*)(ws);                 // 64 MB (reused as sb)
  unsigned short* inpq    = (unsigned short*)(ws + 67108864);      // 128 MB [n][2048]
  unsigned short* gscan   = (unsigned short*)(ws + 201326592);     // 64 MB
  unsigned short* Wb_in   = (unsigned short*)(ws + 268435456);     // 2 MB
  unsigned short* Wb_gate = (unsigned short*)(ws + 270532608);     // 2 MB
  unsigned short* Wb_out  = (unsigned short*)(ws + 272629760);     // 2 MB
  unsigned short* Wcat    = (unsigned short*)(ws + 274726912);     // 4 MB [e][2048]
  unsigned short* Ab      = (unsigned short*)(ws + 278921216);     // 2 MB
  unsigned short* mbuf    = (unsigned short*)(ws + 281018368);     // 32 KB (2x8x1024)
  unsigned int*   flags   = (unsigned int*)(ws + 281051136);       // 256 B (64 flags)
  unsigned int*   ctl     = flags + 64;                            // 256 B election ctl
  float*          vflat   = (float*)d_out;          // v lives in d_out pre-scan
  unsigned short* sbuf    = xb;                     // states overwrite xb

  // prep
  cast_bf16<<<(33554432 / 4 + 255) / 256, 256, 0, stream>>>(x, xb, 33554432);
  cast_bf16<<<1024, 256, 0, stream>>>(W_in,   Wb_in,   1048576);
  cast_bf16<<<1024, 256, 0, stream>>>(W_gate, Wb_gate, 1048576);
  cast_bf16<<<1024, 256, 0, stream>>>(W_out,  Wb_out,  1048576);
  build_wcat<<<1024, 256, 0, stream>>>(Bm, A, Wcat, Ab);
  // zero mbuf(8192 words)+flags(64)+ctl(64); winner word (idx 8192+64+16) = -1
  init_ws<<<(8320 + 255) / 256, 256, 0, stream>>>((unsigned int*)mbuf, 8320, 8272);

  dim3 grid(NTOK / 128, DIM / 128);
  // inp = x @ W_in^T + b_in
  gemm_nt<0><<<grid, 256, 0, stream>>>(xb, DIM, Wb_in, DIM, DIM, b_in,
                                       (void*)inpq, nullptr, nullptr);
  // g = sigmoid(inp @ W_gate^T + b_gate); q = (1-g)*inp
  gemm_nt<1><<<grid, 256, 0, stream>>>(inpq, 2048, Wb_gate, DIM, DIM, b_gate,
                                       (void*)gscan, inpq, inpq);
  // v = [inp, q] @ [B; A]^T   (K = 2048)
  gemm_nt<2><<<grid, 256, 0, stream>>>(inpq, 2048, Wcat, 2048, 2048, b_in,
                                       (void*)vflat, nullptr, nullptr);
  // sequential scan: 256 candidate WGs -> 16-WG single-XCD team
  scan_kernel<<<256, 256, 0, stream>>>(Ab, gscan, vflat, sbuf, mbuf, flags, ctl);
  // out = states @ W_out^T + b_out  (with [t*8+b] -> [b*4096+t] permute)
  gemm_nt<3><<<grid, 256, 0, stream>>>(sbuf, DIM, Wb_out, DIM, DIM, b_out,
                                       (void*)d_out, nullptr, nullptr);
}

// Round 3
// 39299.130 us; speedup vs baseline: 1.0369x; 1.0369x over previous
//
#include <hip/hip_runtime.h>
#include <stdint.h>
#include <stddef.h>

// MambaBlock on MI355X (gfx950).
// out = OutProj( scan_t( s_t = tanh(A(g_t*s_{t-1}) + v_t) ) )
// with v = ((1-g)*inp)@A^T + inp@B^T hoisted into one K=2048 GEMM.
//
// Round 5: TAG-IN-DATA exchange at LLC scope (sc0 sc1 only).
// Round-2 post-mortem: the sc0-only XCD-local probe REJECTED (WRITE_SIZE
// +73MB showed the dual-store LLC fallback ran; scan 45ms). So: LLC scope
// everywhere, but collapse the per-step chain. Round-0's chain was
//   m-store drain -> flag store -> 64-wave flag poll -> m-load -> MFMA
// (~4 LLC hops + poll contention on 4 cachelines). Now freshness travels
// WITH the data: each producer lane stores a 16B slot {tag, d0, d1, tag}
// (one dwordx4, tag = step). Consumers poll the slots directly with
// pipelined tagged loads (2 groups x 8 loads in flight), retrying stale
// groups only. No flags, no producer drain, no separate poll hop; poll
// traffic spread over 256 cachelines. Parity reuse is safe without any
// barrier: overwriting parity p for step t+1 requires having consumed all
// of step t, which implies every wave published step t, which implies no
// wave still needs step t-1 (the old occupant of p). Torn reads guarded
// by dual tags + bounded retry (256/group/step -> bug degrades to a
// wrong-answer report, never a hang).

#define DIM   1024
#define SEQ   4096
#define NB    8
#define NTOK  (NB*SEQ)   // 32768

typedef __attribute__((ext_vector_type(8))) short          short8;
typedef __attribute__((ext_vector_type(4))) float          float4v;
typedef __attribute__((ext_vector_type(4))) int            int4v;
typedef __attribute__((ext_vector_type(4))) unsigned short ushort4v;

__device__ __forceinline__ unsigned short f2b(float f) {
  union { float f; unsigned int u; } v; v.f = f;
  return (unsigned short)((v.u + 0x7FFFu + ((v.u >> 16) & 1u)) >> 16);   // RNE
}
__device__ __forceinline__ float b2f(unsigned short h) {
  union { unsigned int u; float f; } v; v.u = ((unsigned int)h) << 16;
  return v.f;
}

// ---------------------------------------------------------------- small prep
__global__ void cast_bf16(const float* __restrict__ src,
                          unsigned short* __restrict__ dst, int n) {
  int i4 = (blockIdx.x * blockDim.x + threadIdx.x) * 4;
  if (i4 >= n) return;
  float4v v = *(const float4v*)(src + i4);
  ushort4v o;
  o[0] = f2b(v[0]); o[1] = f2b(v[1]); o[2] = f2b(v[2]); o[3] = f2b(v[3]);
  *(ushort4v*)(dst + i4) = o;
}

// Wcat[e][0:1024] = B[e][:], Wcat[e][1024:2048] = A[e][:]; Ab = bf16(A)
__global__ void build_wcat(const float* __restrict__ Bm, const float* __restrict__ A,
                           unsigned short* __restrict__ Wcat,
                           unsigned short* __restrict__ Ab) {
  int i4 = (blockIdx.x * 256 + threadIdx.x) * 4;       // 0..1048572
  int e = i4 >> 10, d = i4 & 1023;
  float4v bv = *(const float4v*)(Bm + i4);
  float4v av = *(const float4v*)(A + i4);
  ushort4v bb, ab;
  #pragma unroll
  for (int r = 0; r < 4; r++) { bb[r] = f2b(bv[r]); ab[r] = f2b(av[r]); }
  *(ushort4v*)(Wcat + (size_t)e * 2048 + d) = bb;
  *(ushort4v*)(Wcat + (size_t)e * 2048 + 1024 + d) = ab;
  *(ushort4v*)(Ab + i4) = ab;
}

__global__ void zero_u32(unsigned int* __restrict__ p, int n) {
  int i = blockIdx.x * 256 + threadIdx.x;
  if (i < n) p[i] = 0u;
}

// ---------------------------------------------------------------- GEMM (NT)
// C[m,n] = sum_k Ag[m,k]*Bg[n,k]  (both K-contiguous), 128x128 tile, BK=64.
// LDS rows padded to 72 elems -> conflict-free b128.
// EPI: 0 inp->inpq[:, :1024] bf16 | 1 gate->gscan bf16 + q->inpq[:,1024:]
//      2 v->fp32 [t*8+b][e]       | 3 out->fp32 [b*4096+t][e]
template<int EPI>
__global__ __launch_bounds__(256, 2)
void gemm_nt(const unsigned short* __restrict__ Ag, int lda,
             const unsigned short* __restrict__ Bg, int ldb,
             int K,
             const float* __restrict__ bias,
             void* __restrict__ out0,
             unsigned short* __restrict__ out1,
             const unsigned short* __restrict__ aux) {
  __shared__ unsigned short sA[128 * 72];
  __shared__ unsigned short sB[128 * 72];
  const int tid  = threadIdx.x;
  const int lane = tid & 63;
  const int wave = tid >> 6;
  const int wm = wave & 1, wn = wave >> 1;
  const int m0 = blockIdx.x * 128;
  const int n0 = blockIdx.y * 128;
  const int q  = lane >> 4;
  const int ln = lane & 15;

  float4v acc[4][4];
  const float4v fz = {0.f, 0.f, 0.f, 0.f};
  #pragma unroll
  for (int i = 0; i < 4; i++)
    #pragma unroll
    for (int j = 0; j < 4; j++) acc[i][j] = fz;

  for (int kk = 0; kk < K; kk += 64) {
    __syncthreads();                       // protect LDS reuse
    #pragma unroll
    for (int s = 0; s < 4; s++) {          // stage 128x64 of A and B
      int chunk = tid + s * 256;           // 0..1023 : row*8 + c
      int row = chunk >> 3, c = chunk & 7;
      int4v va = *(const int4v*)(Ag + (size_t)(m0 + row) * lda + kk + c * 8);
      int4v vb = *(const int4v*)(Bg + (size_t)(n0 + row) * ldb + kk + c * 8);
      *(int4v*)(sA + row * 72 + c * 8) = va;
      *(int4v*)(sB + row * 72 + c * 8) = vb;
    }
    __syncthreads();
    #pragma unroll
    for (int ks = 0; ks < 64; ks += 32) {
      short8 af[4], bf[4];
      #pragma unroll
      for (int i = 0; i < 4; i++)
        af[i] = *(const short8*)(sA + (wm * 64 + i * 16 + ln) * 72 + ks + q * 8);
      #pragma unroll
      for (int j = 0; j < 4; j++)
        bf[j] = *(const short8*)(sB + (wn * 64 + j * 16 + ln) * 72 + ks + q * 8);
      #pragma unroll
      for (int i = 0; i < 4; i++)
        #pragma unroll
        for (int j = 0; j < 4; j++)
          acc[i][j] = __builtin_amdgcn_mfma_f32_16x16x32_bf16(af[i], bf[j], acc[i][j], 0, 0, 0);
    }
  }

  #pragma unroll
  for (int j = 0; j < 4; j++) {
    const int gn = n0 + wn * 64 + j * 16 + ln;      // N index (feature e)
    const float bval = (EPI == 2) ? 0.f : bias[gn];
    #pragma unroll
    for (int i = 0; i < 4; i++) {
      const int gm = m0 + wm * 64 + i * 16 + q * 4; // M index (token row)
      #pragma unroll
      for (int r = 0; r < 4; r++) {
        const int row = gm + r;
        float vv = acc[i][j][r] + bval;
        if constexpr (EPI == 0) {
          ((unsigned short*)out0)[(size_t)row * 2048 + gn] = f2b(vv);
        } else if constexpr (EPI == 1) {
          float g = 1.f / (1.f + __expf(-vv));
          int t = row & (SEQ - 1), b = row >> 12;   // token row = b*SEQ + t
          ((unsigned short*)out0)[(size_t)(t * NB + b) * DIM + gn] = f2b(g);
          float iv = b2f(aux[(size_t)row * 2048 + gn]);
          out1[(size_t)row * 2048 + 1024 + gn] = f2b((1.f - g) * iv);
        } else if constexpr (EPI == 2) {
          int t = row & (SEQ - 1), b = row >> 12;
          ((float*)out0)[(size_t)(t * NB + b) * DIM + gn] = vv;
        } else {                                    // row = t*8 + b
          int b = row & 7, t = row >> 3;
          ((float*)out0)[(size_t)(b * SEQ + t) * DIM + gn] = vv;
        }
      }
    }
  }
}

// ---------------------------------------------------------------- scan helpers
// Tagged slot layout: one 16B slot per 4 bf16 m-values:
//   { tag(u32), data0(2xbf16), data1(2xbf16), tag(u32) }, tag = step index.
// Slot for elem (b, e): byte offset (b*1024 + e) * 4 within a 32KB parity
// block; two parity blocks (64KB total). Fragment ks of a consumer lane
// (q, bcl) = m[bcl][ks*32 + q*8 .. +8] = two consecutive slots at
//   bcl*4096 + ks*128 + q*32  (+0, +16).

template<int G>
__device__ __forceinline__ void issue8(const char* cb, int4v* s) {
  #pragma unroll
  for (int j = 0; j < 4; j++) {
    asm volatile("global_load_dwordx4 %0, %1, off offset:%2 sc0 sc1"
                 : "=v"(s[2 * j])     : "v"(cb), "n"(G * 512 + j * 128));
    asm volatile("global_load_dwordx4 %0, %1, off offset:%2 sc0 sc1"
                 : "=v"(s[2 * j + 1]) : "v"(cb), "n"(G * 512 + j * 128 + 16));
  }
}

#define WAITV8(s)                                                   \
  asm volatile("s_waitcnt vmcnt(8)"                                 \
    : "+v"((s)[0]), "+v"((s)[1]), "+v"((s)[2]), "+v"((s)[3]),       \
      "+v"((s)[4]), "+v"((s)[5]), "+v"((s)[6]), "+v"((s)[7]) :: "memory")
#define WAITV0(s)                                                   \
  asm volatile("s_waitcnt vmcnt(0)"                                 \
    : "+v"((s)[0]), "+v"((s)[1]), "+v"((s)[2]), "+v"((s)[3]),       \
      "+v"((s)[4]), "+v"((s)[5]), "+v"((s)[6]), "+v"((s)[7]) :: "memory")

// Wait for group G, verify 16 tag words (retry stale, bounded), 4 MFMAs.
// Issues group G+1 first so its loads overlap G's validation+compute.
template<int G>
__device__ __forceinline__ void consume_group(const char* cb, int4v* sl,
                                              const short8* af, float4v* aa,
                                              const int tgt) {
  int4v* sg = sl + ((G & 1) * 8);
  if constexpr (G < 7) issue8<G + 1>(cb, sl + (((G + 1) & 1) * 8));
  if constexpr (G < 7) { WAITV8(sg); } else { WAITV0(sg); }
  int tries = 0;
  for (;;) {
    int bad = 0;
    #pragma unroll
    for (int j = 0; j < 4; j++) {
      bad |= (sg[2 * j][0] ^ tgt) | (sg[2 * j][3] ^ tgt) |
             (sg[2 * j + 1][0] ^ tgt) | (sg[2 * j + 1][3] ^ tgt);
    }
    if (__all(bad == 0) || ++tries > 256) break;   // bounded: bug -> wrong, not hung
    __builtin_amdgcn_s_sleep(2);
    issue8<G>(cb, sg);
    WAITV0(sg);
  }
  #pragma unroll
  for (int j = 0; j < 4; j++) {
    int4v fd;
    fd[0] = sg[2 * j][1];     fd[1] = sg[2 * j][2];
    fd[2] = sg[2 * j + 1][1]; fd[3] = sg[2 * j + 1][2];
    union { int4v i; short8 s; } cv; cv.i = fd;
    aa[j] = __builtin_amdgcn_mfma_f32_16x16x32_bf16(af[4 * G + j], cv.s, aa[j], 0, 0, 0);
  }
}

// ---------------------------------------------------------------- scan
// 16 WGs x 256 thr = 64 waves; wave gw owns e-rows [16*gw, 16*gw+16).
// Per step: prefetch v_t/g_{t+1} (cached) -> 8 pipelined tagged-slot groups
// (poll data directly; 4 MFMAs per validated group) -> tanh epi -> sb store
// (cached) + tagged m-store (sc0 sc1, fire-and-forget). No flags, no drains,
// no __syncthreads.
__global__ __launch_bounds__(256, 1)
void scan_kernel(const unsigned short* __restrict__ Ab,     // [1024][1024] bf16
                 const unsigned short* __restrict__ gscan,  // [t*8+b][1024] bf16
                 const float* __restrict__ vflat,           // [t*8+b][1024] f32
                 unsigned short* __restrict__ sb,           // [t*8+b][1024] bf16
                 char* __restrict__ mtag) {                 // [2][32KB] tagged slots
  const int tid  = threadIdx.x;
  const int lane = tid & 63;
  const int wave = tid >> 6;
  const int gw   = blockIdx.x * 4 + wave;    // 0..63
  const int e0   = gw * 16;
  const int q    = lane >> 4;
  const int ln   = lane & 15;
  const int bcl  = ln & 7;                   // clamped batch (cols 8-15 unused)
  const bool active = (ln < 8);
  const int eb = e0 + q * 4;

  short8 af[32];                             // A rows in registers (128 VGPRs)
  #pragma unroll
  for (int ks = 0; ks < 32; ks++)
    af[ks] = *(const short8*)(Ab + (size_t)(e0 + ln) * 1024 + ks * 32 + q * 8);

  const int   cload = bcl * 4096 + q * 32;            // consumer lane offset
  const int   pslot = (bcl * 1024 + eb) * 4;          // producer slot offset
  const float4v fz = {0.f, 0.f, 0.f, 0.f};

  for (int t = 0; t < SEQ; t++) {
    // prefetch v_t and g_{t+1} — plain cached loads, drained by first WAITV8
    float4v vv = fz;
    ushort4v g4 = {0, 0, 0, 0};
    size_t rowoff = (size_t)(t * NB + bcl) * DIM + eb;
    if (active) {
      vv = *(const float4v*)(vflat + rowoff);
      if (t < SEQ - 1)
        g4 = *(const ushort4v*)(gscan + (size_t)((t + 1) * NB + bcl) * DIM + eb);
    }

    const char* cb = mtag + ((t & 1) << 15) + cload;
    int4v sl[16];                            // 2 groups in flight (64 VGPRs)
    issue8<0>(cb, sl);
    float4v aa[4] = {fz, fz, fz, fz};
    consume_group<0>(cb, sl, af, aa, t);
    consume_group<1>(cb, sl, af, aa, t);
    consume_group<2>(cb, sl, af, aa, t);
    consume_group<3>(cb, sl, af, aa, t);
    consume_group<4>(cb, sl, af, aa, t);
    consume_group<5>(cb, sl, af, aa, t);
    consume_group<6>(cb, sl, af, aa, t);
    consume_group<7>(cb, sl, af, aa, t);

    if (active) {
      float sv[4];
      #pragma unroll
      for (int r = 0; r < 4; r++) {
        float xx = aa[0][r] + aa[1][r] + aa[2][r] + aa[3][r] + vv[r];
        float ex = __expf(-2.f * fabsf(xx));
        float th = (1.f - ex) / (1.f + ex);
        sv[r] = copysignf(th, xx);
      }
      ushort4v sp;
      #pragma unroll
      for (int r = 0; r < 4; r++) sp[r] = f2b(sv[r]);
      *(ushort4v*)(sb + rowoff) = sp;                       // state for out-proj
      if (t < SEQ - 1) {                                    // m_{t+1} = g*s, tagged
        int d0 = (int)((unsigned int)f2b(b2f(g4[0]) * sv[0]) |
                       ((unsigned int)f2b(b2f(g4[1]) * sv[1]) << 16));
        int d1 = (int)((unsigned int)f2b(b2f(g4[2]) * sv[2]) |
                       ((unsigned int)f2b(b2f(g4[3]) * sv[3]) << 16));
        int4v st;
        st[0] = t + 1; st[1] = d0; st[2] = d1; st[3] = t + 1;
        char* mp = mtag + (((t + 1) & 1) << 15) + pslot;
        asm volatile("global_store_dwordx4 %0, %1, off sc0 sc1"
                     :: "v"(mp), "v"(st) : "memory");
      }
    }
  }
}

// ---------------------------------------------------------------- launch
extern "C" void kernel_launch(void* const* d_in, const int* in_sizes, int n_in,
                              void* d_out, int out_size, void* d_ws, size_t ws_size,
                              hipStream_t stream) {
  const float* x      = (const float*)d_in[0];
  const float* A      = (const float*)d_in[1];
  const float* Bm     = (const float*)d_in[2];
  const float* W_in   = (const float*)d_in[3];
  const float* b_in   = (const float*)d_in[4];
  const float* W_gate = (const float*)d_in[5];
  const float* b_gate = (const float*)d_in[6];
  const float* W_out  = (const float*)d_in[7];
  const float* b_out  = (const float*)d_in[8];

  char* ws = (char*)d_ws;
  // workspace layout (~281 MB total)
  unsigned short* xb      = (unsigned short*)(ws);                 // 64 MB (reused as sb)
  unsigned short* inpq    = (unsigned short*)(ws + 67108864);      // 128 MB [n][2048]
  unsigned short* gscan   = (unsigned short*)(ws + 201326592);     // 64 MB
  unsigned short* Wb_in   = (unsigned short*)(ws + 268435456);     // 2 MB
  unsigned short* Wb_gate = (unsigned short*)(ws + 270532608);     // 2 MB
  unsigned short* Wb_out  = (unsigned short*)(ws + 272629760);     // 2 MB
  unsigned short* Wcat    = (unsigned short*)(ws + 274726912);     // 4 MB [e][2048]
  unsigned short* Ab      = (unsigned short*)(ws + 278921216);     // 2 MB
  char*           mtag    = (char*)inpq;            // 64 KB tagged slots (inpq dead
                                                    // after gemm<2>; zeroed just before scan)
  float*          vflat   = (float*)d_out;          // v lives in d_out pre-scan
  unsigned short* sbuf    = xb;                     // states overwrite xb

  // prep
  cast_bf16<<<(33554432 / 4 + 255) / 256, 256, 0, stream>>>(x, xb, 33554432);
  cast_bf16<<<1024, 256, 0, stream>>>(W_in,   Wb_in,   1048576);
  cast_bf16<<<1024, 256, 0, stream>>>(W_gate, Wb_gate, 1048576);
  cast_bf16<<<1024, 256, 0, stream>>>(W_out,  Wb_out,  1048576);
  build_wcat<<<1024, 256, 0, stream>>>(Bm, A, Wcat, Ab);

  dim3 grid(NTOK / 128, DIM / 128);
  // inp = x @ W_in^T + b_in
  gemm_nt<0><<<grid, 256, 0, stream>>>(xb, DIM, Wb_in, DIM, DIM, b_in,
                                       (void*)inpq, nullptr, nullptr);
  // g = sigmoid(inp @ W_gate^T + b_gate); q = (1-g)*inp
  gemm_nt<1><<<grid, 256, 0, stream>>>(inpq, 2048, Wb_gate, DIM, DIM, b_gate,
                                       (void*)gscan, inpq, inpq);
  // v = [inp, q] @ [B; A]^T   (K = 2048)
  gemm_nt<2><<<grid, 256, 0, stream>>>(inpq, 2048, Wcat, 2048, 2048, b_in,
                                       (void*)vflat, nullptr, nullptr);
  // zero the tagged-slot region (tag 0 == valid m_0 = 0), then scan
  zero_u32<<<(16384 + 255) / 256, 256, 0, stream>>>((unsigned int*)mtag, 16384);
  scan_kernel<<<16, 256, 0, stream>>>(Ab, gscan, vflat, sbuf, mtag);
  // out = states @ W_out^T + b_out  (with [t*8+b] -> [b*4096+t] permute)
  gemm_nt<3><<<grid, 256, 0, stream>>>(sbuf, Wb_out == nullptr ? DIM : DIM, Wb_out, DIM, DIM, b_out,
                                       (void*)d_out, nullptr, nullptr);
}

// Round 4
// 25658.524 us; speedup vs baseline: 1.5881x; 1.5316x over previous
//
#include <hip/hip_runtime.h>
#include <stdint.h>
#include <stddef.h>

// MambaBlock on MI355X (gfx950).
// out = OutProj( scan_t( s_t = tanh(A(g_t*s_{t-1}) + v_t) ) )
// with v = ((1-g)*inp)@A^T + inp@B^T hoisted into one K=2048 GEMM.
//
// Round 6: round-0 flag protocol (best measured: 28.3ms scan) + two latency
// cuts, everything else byte-identical:
//  1. WG-aggregated flags + designated poller: 4 waves/WG barrier locally,
//     wave0 stores ONE per-WG flag (16 flags = one cacheline); only wave0 of
//     each WG polls globally (16 pollers x 1 line vs 64 x 4 lines = ~16x less
//     LLC slice pressure), siblings released via an LDS counter.
//  2. v/g prefetch software-pipelined one step ahead: round-0 issued the
//     prefetch right before the poll, whose vmcnt(0) serialized ~1us of HBM
//     latency into every step. Now step t issues loads for t+1 (inline asm,
//     BEFORE the m-loads so they are older ops; in-order vmcnt retirement
//     keeps the staged 28-4c constants exact) and consumes carried registers.
// Tag-in-data (round 5) regressed: FETCH 2x, retry storms. Reverted.

#define DIM   1024
#define SEQ   4096
#define NB    8
#define NTOK  (NB*SEQ)   // 32768

typedef __attribute__((ext_vector_type(8))) short          short8;
typedef __attribute__((ext_vector_type(4))) float          float4v;
typedef __attribute__((ext_vector_type(4))) int            int4v;
typedef __attribute__((ext_vector_type(4))) unsigned short ushort4v;

__device__ __forceinline__ unsigned short f2b(float f) {
  union { float f; unsigned int u; } v; v.f = f;
  return (unsigned short)((v.u + 0x7FFFu + ((v.u >> 16) & 1u)) >> 16);   // RNE
}
__device__ __forceinline__ float b2f(unsigned short h) {
  union { unsigned int u; float f; } v; v.u = ((unsigned int)h) << 16;
  return v.f;
}

// ---------------------------------------------------------------- small prep
__global__ void cast_bf16(const float* __restrict__ src,
                          unsigned short* __restrict__ dst, int n) {
  int i4 = (blockIdx.x * blockDim.x + threadIdx.x) * 4;
  if (i4 >= n) return;
  float4v v = *(const float4v*)(src + i4);
  ushort4v o;
  o[0] = f2b(v[0]); o[1] = f2b(v[1]); o[2] = f2b(v[2]); o[3] = f2b(v[3]);
  *(ushort4v*)(dst + i4) = o;
}

// Wcat[e][0:1024] = B[e][:], Wcat[e][1024:2048] = A[e][:]; Ab = bf16(A)
__global__ void build_wcat(const float* __restrict__ Bm, const float* __restrict__ A,
                           unsigned short* __restrict__ Wcat,
                           unsigned short* __restrict__ Ab) {
  int i4 = (blockIdx.x * 256 + threadIdx.x) * 4;       // 0..1048572
  int e = i4 >> 10, d = i4 & 1023;
  float4v bv = *(const float4v*)(Bm + i4);
  float4v av = *(const float4v*)(A + i4);
  ushort4v bb, ab;
  #pragma unroll
  for (int r = 0; r < 4; r++) { bb[r] = f2b(bv[r]); ab[r] = f2b(av[r]); }
  *(ushort4v*)(Wcat + (size_t)e * 2048 + d) = bb;
  *(ushort4v*)(Wcat + (size_t)e * 2048 + 1024 + d) = ab;
  *(ushort4v*)(Ab + i4) = ab;
}

__global__ void zero_u32(unsigned int* __restrict__ p, int n) {
  int i = blockIdx.x * 256 + threadIdx.x;
  if (i < n) p[i] = 0u;
}

// ---------------------------------------------------------------- GEMM (NT)
// C[m,n] = sum_k Ag[m,k]*Bg[n,k]  (both K-contiguous), 128x128 tile, BK=64.
// LDS rows padded to 72 elems -> conflict-free b128.
// EPI: 0 inp->inpq[:, :1024] bf16 | 1 gate->gscan bf16 + q->inpq[:,1024:]
//      2 v->fp32 [t*8+b][e]       | 3 out->fp32 [b*4096+t][e]
template<int EPI>
__global__ __launch_bounds__(256, 2)
void gemm_nt(const unsigned short* __restrict__ Ag, int lda,
             const unsigned short* __restrict__ Bg, int ldb,
             int K,
             const float* __restrict__ bias,
             void* __restrict__ out0,
             unsigned short* __restrict__ out1,
             const unsigned short* __restrict__ aux) {
  __shared__ unsigned short sA[128 * 72];
  __shared__ unsigned short sB[128 * 72];
  const int tid  = threadIdx.x;
  const int lane = tid & 63;
  const int wave = tid >> 6;
  const int wm = wave & 1, wn = wave >> 1;
  const int m0 = blockIdx.x * 128;
  const int n0 = blockIdx.y * 128;
  const int q  = lane >> 4;
  const int ln = lane & 15;

  float4v acc[4][4];
  const float4v fz = {0.f, 0.f, 0.f, 0.f};
  #pragma unroll
  for (int i = 0; i < 4; i++)
    #pragma unroll
    for (int j = 0; j < 4; j++) acc[i][j] = fz;

  for (int kk = 0; kk < K; kk += 64) {
    __syncthreads();                       // protect LDS reuse
    #pragma unroll
    for (int s = 0; s < 4; s++) {          // stage 128x64 of A and B
      int chunk = tid + s * 256;           // 0..1023 : row*8 + c
      int row = chunk >> 3, c = chunk & 7;
      int4v va = *(const int4v*)(Ag + (size_t)(m0 + row) * lda + kk + c * 8);
      int4v vb = *(const int4v*)(Bg + (size_t)(n0 + row) * ldb + kk + c * 8);
      *(int4v*)(sA + row * 72 + c * 8) = va;
      *(int4v*)(sB + row * 72 + c * 8) = vb;
    }
    __syncthreads();
    #pragma unroll
    for (int ks = 0; ks < 64; ks += 32) {
      short8 af[4], bf[4];
      #pragma unroll
      for (int i = 0; i < 4; i++)
        af[i] = *(const short8*)(sA + (wm * 64 + i * 16 + ln) * 72 + ks + q * 8);
      #pragma unroll
      for (int j = 0; j < 4; j++)
        bf[j] = *(const short8*)(sB + (wn * 64 + j * 16 + ln) * 72 + ks + q * 8);
      #pragma unroll
      for (int i = 0; i < 4; i++)
        #pragma unroll
        for (int j = 0; j < 4; j++)
          acc[i][j] = __builtin_amdgcn_mfma_f32_16x16x32_bf16(af[i], bf[j], acc[i][j], 0, 0, 0);
    }
  }

  #pragma unroll
  for (int j = 0; j < 4; j++) {
    const int gn = n0 + wn * 64 + j * 16 + ln;      // N index (feature e)
    const float bval = (EPI == 2) ? 0.f : bias[gn];
    #pragma unroll
    for (int i = 0; i < 4; i++) {
      const int gm = m0 + wm * 64 + i * 16 + q * 4; // M index (token row)
      #pragma unroll
      for (int r = 0; r < 4; r++) {
        const int row = gm + r;
        float vv = acc[i][j][r] + bval;
        if constexpr (EPI == 0) {
          ((unsigned short*)out0)[(size_t)row * 2048 + gn] = f2b(vv);
        } else if constexpr (EPI == 1) {
          float g = 1.f / (1.f + __expf(-vv));
          int t = row & (SEQ - 1), b = row >> 12;   // token row = b*SEQ + t
          ((unsigned short*)out0)[(size_t)(t * NB + b) * DIM + gn] = f2b(g);
          float iv = b2f(aux[(size_t)row * 2048 + gn]);
          out1[(size_t)row * 2048 + 1024 + gn] = f2b((1.f - g) * iv);
        } else if constexpr (EPI == 2) {
          int t = row & (SEQ - 1), b = row >> 12;
          ((float*)out0)[(size_t)(t * NB + b) * DIM + gn] = vv;
        } else {                                    // row = t*8 + b
          int b = row & 7, t = row >> 3;
          ((float*)out0)[(size_t)(b * SEQ + t) * DIM + gn] = vv;
        }
      }
    }
  }
}

// ---------------------------------------------------------------- scan
// 16 WGs x 256 thr = 64 waves; wave gw owns e-rows [16*gw, 16*gw+16).
// Per step: [wave0: poll 16 WG-flags (1 line, sc0 sc1) -> LDS release |
// others: LDS spin] -> issue next-step v/g prefetch (asm, oldest ops) ->
// 32x dwordx4 sc0 sc1 m-loads, staged vmcnt waits (28-4c, exact: prefetches
// are older, vmcnt retires in order) -> 32 MFMAs -> tanh epi (carried v/g)
// -> sb store + m-store -> vmcnt(0) -> s_barrier -> wave0-lane0 WG-flag.
__global__ __launch_bounds__(256, 1)
void scan_kernel(const unsigned short* __restrict__ Ab,     // [1024][1024] bf16
                 const unsigned short* __restrict__ gscan,  // [t*8+b][1024] bf16
                 const float* __restrict__ vflat,           // [t*8+b][1024] f32
                 unsigned short* __restrict__ sb,           // [t*8+b][1024] bf16
                 unsigned short* __restrict__ mbuf,         // [2][8][1024] bf16
                 unsigned int* __restrict__ flags) {        // [16] per-WG
  const int tid  = threadIdx.x;
  const int lane = tid & 63;
  const int wave = tid >> 6;
  const int gw   = blockIdx.x * 4 + wave;    // 0..63
  const int e0   = gw * 16;
  const int q    = lane >> 4;
  const int ln   = lane & 15;
  const int bcl  = ln & 7;                   // clamped batch (n>=8 unused cols)
  const bool active = (ln < 8);
  const int eb = e0 + q * 4;

  __shared__ volatile int sready;
  if (tid == 0) sready = 0;                  // t=0 passes without a poll
  __syncthreads();

  short8 af[32];                             // A rows in registers
  #pragma unroll
  for (int ks = 0; ks < 32; ks++)
    af[ks] = *(const short8*)(Ab + (size_t)(e0 + ln) * 1024 + ks * 32 + q * 8);

  const unsigned int* fpoll = flags + (lane & 15);   // 16 flags, one line
  unsigned int* const myflag = flags + blockIdx.x;
  const float4v fz = {0.f, 0.f, 0.f, 0.f};

  // prologue: prefetch v_0 and g_1 (consumed at t=0)
  float4v vv = fz;
  ushort4v g4 = {0, 0, 0, 0};
  if (active) {
    vv = *(const float4v*)(vflat + (size_t)bcl * DIM + eb);
    g4 = *(const ushort4v*)(gscan + (size_t)(NB + bcl) * DIM + eb);
  }

  for (int t = 0; t < SEQ; t++) {
    // ---- sync: wave0 polls globally, releases siblings through LDS
    if (wave == 0) {
      const unsigned int target = (unsigned int)t;
      for (;;) {
        unsigned int pv;
        asm volatile("global_load_dword %0, %1, off sc0 sc1\n\t"
                     "s_waitcnt vmcnt(0)"
                     : "=&v"(pv) : "v"(fpoll) : "memory");
        if (__all((int)(pv >= target))) break;
      }
      sready = t;
    } else {
      while (sready < t) { }                 // LDS spin (~120cy/ds_read, local)
    }

    // ---- prefetch NEXT step's v/g (plain cached, oldest ops this step)
    const int tn = (t + 1 < SEQ) ? t + 1 : SEQ - 1;
    const int tg = (t + 2 < SEQ) ? t + 2 : SEQ - 1;
    const float* vp = vflat + (size_t)(tn * NB + bcl) * DIM + eb;
    const unsigned short* gp = gscan + (size_t)(tg * NB + bcl) * DIM + eb;
    float4v vv_n;
    ushort4v g4_n;
    asm volatile("global_load_dwordx4 %0, %1, off" : "=v"(vv_n) : "v"(vp));
    asm volatile("global_load_dwordx2 %0, %1, off" : "=v"(g4_n) : "v"(gp));

    // ---- load m_t fragments straight from LLC (sc0 sc1), staged waits
    const unsigned short* mb = mbuf + (size_t)(t & 1) * (NB * DIM);
    const unsigned short* mbp = mb + bcl * DIM + q * 8;
    short8 fr[32];
    #pragma unroll
    for (int ks = 0; ks < 32; ks++)
      asm volatile("global_load_dwordx4 %0, %1, off offset:%2 sc0 sc1"
                   : "=v"(fr[ks]) : "v"(mbp), "n"(ks * 64));

    float4v a0 = fz, a1 = fz, a2 = fz, a3 = fz;
    #pragma unroll
    for (int c = 0; c < 8; c++) {
      asm volatile("s_waitcnt vmcnt(%4)"
                   : "+v"(fr[4 * c]), "+v"(fr[4 * c + 1]),
                     "+v"(fr[4 * c + 2]), "+v"(fr[4 * c + 3])
                   : "n"(28 - 4 * c));
      a0 = __builtin_amdgcn_mfma_f32_16x16x32_bf16(af[4 * c + 0], fr[4 * c + 0], a0, 0, 0, 0);
      a1 = __builtin_amdgcn_mfma_f32_16x16x32_bf16(af[4 * c + 1], fr[4 * c + 1], a1, 0, 0, 0);
      a2 = __builtin_amdgcn_mfma_f32_16x16x32_bf16(af[4 * c + 2], fr[4 * c + 2], a2, 0, 0, 0);
      a3 = __builtin_amdgcn_mfma_f32_16x16x32_bf16(af[4 * c + 3], fr[4 * c + 3], a3, 0, 0, 0);
    }

    if (active) {
      size_t rowoff = (size_t)(t * NB + bcl) * DIM + eb;
      float sv[4];
      #pragma unroll
      for (int r = 0; r < 4; r++) {
        float xx = a0[r] + a1[r] + a2[r] + a3[r] + vv[r];
        float ex = __expf(-2.f * fabsf(xx));
        float th = (1.f - ex) / (1.f + ex);
        sv[r] = copysignf(th, xx);
      }
      ushort4v sp;
      #pragma unroll
      for (int r = 0; r < 4; r++) sp[r] = f2b(sv[r]);
      *(ushort4v*)(sb + rowoff) = sp;                       // state for out-proj
      if (t < SEQ - 1) {                                    // m_{t+1} = g*s
        unsigned long long mv =
            (unsigned long long)((unsigned int)f2b(b2f(g4[0]) * sv[0]) |
                                 ((unsigned int)f2b(b2f(g4[1]) * sv[1]) << 16)) |
            ((unsigned long long)((unsigned int)f2b(b2f(g4[2]) * sv[2]) |
                                  ((unsigned int)f2b(b2f(g4[3]) * sv[3]) << 16)) << 32);
        unsigned short* mn = mbuf + (size_t)((t + 1) & 1) * (NB * DIM) + bcl * DIM + eb;
        asm volatile("global_store_dwordx2 %0, %1, off sc0 sc1"
                     :: "v"(mn), "v"(mv) : "memory");
      }
    }

    vv = vv_n;                               // carry next step's operands
    g4 = g4_n;

    if (t == SEQ - 1) break;

    // publish: drain m-store to the coherence point, WG barrier, one flag
    asm volatile("s_waitcnt vmcnt(0)" ::: "memory");
    __builtin_amdgcn_s_barrier();
    if (tid == 0) {
      unsigned int fv = (unsigned int)(t + 1);
      asm volatile("global_store_dword %0, %1, off sc0 sc1"
                   :: "v"(myflag), "v"(fv) : "memory");
    }
  }
}

// ---------------------------------------------------------------- launch
extern "C" void kernel_launch(void* const* d_in, const int* in_sizes, int n_in,
                              void* d_out, int out_size, void* d_ws, size_t ws_size,
                              hipStream_t stream) {
  const float* x      = (const float*)d_in[0];
  const float* A      = (const float*)d_in[1];
  const float* Bm     = (const float*)d_in[2];
  const float* W_in   = (const float*)d_in[3];
  const float* b_in   = (const float*)d_in[4];
  const float* W_gate = (const float*)d_in[5];
  const float* b_gate = (const float*)d_in[6];
  const float* W_out  = (const float*)d_in[7];
  const float* b_out  = (const float*)d_in[8];

  char* ws = (char*)d_ws;
  // workspace layout (~281 MB total)
  unsigned short* xb      = (unsigned short*)(ws);                 // 64 MB (reused as sb)
  unsigned short* inpq    = (unsigned short*)(ws + 67108864);      // 128 MB [n][2048]
  unsigned short* gscan   = (unsigned short*)(ws + 201326592);     // 64 MB
  unsigned short* Wb_in   = (unsigned short*)(ws + 268435456);     // 2 MB
  unsigned short* Wb_gate = (unsigned short*)(ws + 270532608);     // 2 MB
  unsigned short* Wb_out  = (unsigned short*)(ws + 272629760);     // 2 MB
  unsigned short* Wcat    = (unsigned short*)(ws + 274726912);     // 4 MB [e][2048]
  unsigned short* Ab      = (unsigned short*)(ws + 278921216);     // 2 MB
  unsigned short* mbuf    = (unsigned short*)(ws + 281018368);     // 32 KB (2x8x1024)
  unsigned int*   flags   = (unsigned int*)(ws + 281051136);       // 64 B (16 WG flags)
  float*          vflat   = (float*)d_out;          // v lives in d_out pre-scan
  unsigned short* sbuf    = xb;                     // states overwrite xb

  // prep
  cast_bf16<<<(33554432 / 4 + 255) / 256, 256, 0, stream>>>(x, xb, 33554432);
  cast_bf16<<<1024, 256, 0, stream>>>(W_in,   Wb_in,   1048576);
  cast_bf16<<<1024, 256, 0, stream>>>(W_gate, Wb_gate, 1048576);
  cast_bf16<<<1024, 256, 0, stream>>>(W_out,  Wb_out,  1048576);
  build_wcat<<<1024, 256, 0, stream>>>(Bm, A, Wcat, Ab);
  // zero mbuf (8192 u32) + 16 WG flags
  zero_u32<<<(8208 + 255) / 256, 256, 0, stream>>>((unsigned int*)mbuf, 8208);

  dim3 grid(NTOK / 128, DIM / 128);
  // inp = x @ W_in^T + b_in
  gemm_nt<0><<<grid, 256, 0, stream>>>(xb, DIM, Wb_in, DIM, DIM, b_in,
                                       (void*)inpq, nullptr, nullptr);
  // g = sigmoid(inp @ W_gate^T + b_gate); q = (1-g)*inp
  gemm_nt<1><<<grid, 256, 0, stream>>>(inpq, 2048, Wb_gate, DIM, DIM, b_gate,
                                       (void*)gscan, inpq, inpq);
  // v = [inp, q] @ [B; A]^T   (K = 2048)
  gemm_nt<2><<<grid, 256, 0, stream>>>(inpq, 2048, Wcat, 2048, 2048, b_in,
                                       (void*)vflat, nullptr, nullptr);
  // sequential scan
  scan_kernel<<<16, 256, 0, stream>>>(Ab, gscan, vflat, sbuf, mbuf, flags);
  // out = states @ W_out^T + b_out  (with [t*8+b] -> [b*4096+t] permute)
  gemm_nt<3><<<grid, 256, 0, stream>>>(sbuf, DIM, Wb_out, DIM, DIM, b_out,
                                       (void*)d_out, nullptr, nullptr);
}

// Round 5
// 25050.749 us; speedup vs baseline: 1.6267x; 1.0243x over previous
//
#include <hip/hip_runtime.h>
#include <stdint.h>
#include <stddef.h>

// MambaBlock on MI355X (gfx950).
// out = OutProj( scan_t( s_t = tanh(A(g_t*s_{t-1}) + v_t) ) )
// with v = ((1-g)*inp)@A^T + inp@B^T hoisted into one K=2048 GEMM.
//
// Round 7: LLC-RESIDENT EXCHANGE VIA ATOMICS.
// Round-4 post-mortem: WRITE_SIZE 133MB (= sb 64 + m 67) and FETCH 364MB
// (= streams 194 + ~170 m-refetch) prove the sc0|sc1 m/flag stores WRITE
// THROUGH to HBM and the consumer loads MISS and re-read from HBM -> every
// sync hop is an HBM round trip (~1-1.4us), chain ~6us/step.
// Fix: transport = ATOMICS. global_atomic_swap(_x2) executes at the LLC
// slice and leaves the line resident there: store-ack at LLC latency, and
// consumer sc0 sc1 loads become LLC hits. Plus a 2-deep pipelined flag poll
// (observe a set flag at ~T+L instead of ~T+2L); siblings released via LDS
// before the poller drains its leftover load, so the staged 28-4c vmcnt
// constants stay exact for every wave.
// Signature counters if theory holds: WRITE_SIZE -> ~67MB, FETCH -> ~200MB.

#define DIM   1024
#define SEQ   4096
#define NB    8
#define NTOK  (NB*SEQ)   // 32768

typedef __attribute__((ext_vector_type(8))) short          short8;
typedef __attribute__((ext_vector_type(4))) float          float4v;
typedef __attribute__((ext_vector_type(4))) int            int4v;
typedef __attribute__((ext_vector_type(4))) unsigned short ushort4v;

__device__ __forceinline__ unsigned short f2b(float f) {
  union { float f; unsigned int u; } v; v.f = f;
  return (unsigned short)((v.u + 0x7FFFu + ((v.u >> 16) & 1u)) >> 16);   // RNE
}
__device__ __forceinline__ float b2f(unsigned short h) {
  union { unsigned int u; float f; } v; v.u = ((unsigned int)h) << 16;
  return v.f;
}

// ---------------------------------------------------------------- small prep
__global__ void cast_bf16(const float* __restrict__ src,
                          unsigned short* __restrict__ dst, int n) {
  int i4 = (blockIdx.x * blockDim.x + threadIdx.x) * 4;
  if (i4 >= n) return;
  float4v v = *(const float4v*)(src + i4);
  ushort4v o;
  o[0] = f2b(v[0]); o[1] = f2b(v[1]); o[2] = f2b(v[2]); o[3] = f2b(v[3]);
  *(ushort4v*)(dst + i4) = o;
}

// Wcat[e][0:1024] = B[e][:], Wcat[e][1024:2048] = A[e][:]; Ab = bf16(A)
__global__ void build_wcat(const float* __restrict__ Bm, const float* __restrict__ A,
                           unsigned short* __restrict__ Wcat,
                           unsigned short* __restrict__ Ab) {
  int i4 = (blockIdx.x * 256 + threadIdx.x) * 4;       // 0..1048572
  int e = i4 >> 10, d = i4 & 1023;
  float4v bv = *(const float4v*)(Bm + i4);
  float4v av = *(const float4v*)(A + i4);
  ushort4v bb, ab;
  #pragma unroll
  for (int r = 0; r < 4; r++) { bb[r] = f2b(bv[r]); ab[r] = f2b(av[r]); }
  *(ushort4v*)(Wcat + (size_t)e * 2048 + d) = bb;
  *(ushort4v*)(Wcat + (size_t)e * 2048 + 1024 + d) = ab;
  *(ushort4v*)(Ab + i4) = ab;
}

__global__ void zero_u32(unsigned int* __restrict__ p, int n) {
  int i = blockIdx.x * 256 + threadIdx.x;
  if (i < n) p[i] = 0u;
}

// ---------------------------------------------------------------- GEMM (NT)
// C[m,n] = sum_k Ag[m,k]*Bg[n,k]  (both K-contiguous), 128x128 tile, BK=64.
// LDS rows padded to 72 elems -> conflict-free b128.
// EPI: 0 inp->inpq[:, :1024] bf16 | 1 gate->gscan bf16 + q->inpq[:,1024:]
//      2 v->fp32 [t*8+b][e]       | 3 out->fp32 [b*4096+t][e]
template<int EPI>
__global__ __launch_bounds__(256, 2)
void gemm_nt(const unsigned short* __restrict__ Ag, int lda,
             const unsigned short* __restrict__ Bg, int ldb,
             int K,
             const float* __restrict__ bias,
             void* __restrict__ out0,
             unsigned short* __restrict__ out1,
             const unsigned short* __restrict__ aux) {
  __shared__ unsigned short sA[128 * 72];
  __shared__ unsigned short sB[128 * 72];
  const int tid  = threadIdx.x;
  const int lane = tid & 63;
  const int wave = tid >> 6;
  const int wm = wave & 1, wn = wave >> 1;
  const int m0 = blockIdx.x * 128;
  const int n0 = blockIdx.y * 128;
  const int q  = lane >> 4;
  const int ln = lane & 15;

  float4v acc[4][4];
  const float4v fz = {0.f, 0.f, 0.f, 0.f};
  #pragma unroll
  for (int i = 0; i < 4; i++)
    #pragma unroll
    for (int j = 0; j < 4; j++) acc[i][j] = fz;

  for (int kk = 0; kk < K; kk += 64) {
    __syncthreads();                       // protect LDS reuse
    #pragma unroll
    for (int s = 0; s < 4; s++) {          // stage 128x64 of A and B
      int chunk = tid + s * 256;           // 0..1023 : row*8 + c
      int row = chunk >> 3, c = chunk & 7;
      int4v va = *(const int4v*)(Ag + (size_t)(m0 + row) * lda + kk + c * 8);
      int4v vb = *(const int4v*)(Bg + (size_t)(n0 + row) * ldb + kk + c * 8);
      *(int4v*)(sA + row * 72 + c * 8) = va;
      *(int4v*)(sB + row * 72 + c * 8) = vb;
    }
    __syncthreads();
    #pragma unroll
    for (int ks = 0; ks < 64; ks += 32) {
      short8 af[4], bf[4];
      #pragma unroll
      for (int i = 0; i < 4; i++)
        af[i] = *(const short8*)(sA + (wm * 64 + i * 16 + ln) * 72 + ks + q * 8);
      #pragma unroll
      for (int j = 0; j < 4; j++)
        bf[j] = *(const short8*)(sB + (wn * 64 + j * 16 + ln) * 72 + ks + q * 8);
      #pragma unroll
      for (int i = 0; i < 4; i++)
        #pragma unroll
        for (int j = 0; j < 4; j++)
          acc[i][j] = __builtin_amdgcn_mfma_f32_16x16x32_bf16(af[i], bf[j], acc[i][j], 0, 0, 0);
    }
  }

  #pragma unroll
  for (int j = 0; j < 4; j++) {
    const int gn = n0 + wn * 64 + j * 16 + ln;      // N index (feature e)
    const float bval = (EPI == 2) ? 0.f : bias[gn];
    #pragma unroll
    for (int i = 0; i < 4; i++) {
      const int gm = m0 + wm * 64 + i * 16 + q * 4; // M index (token row)
      #pragma unroll
      for (int r = 0; r < 4; r++) {
        const int row = gm + r;
        float vv = acc[i][j][r] + bval;
        if constexpr (EPI == 0) {
          ((unsigned short*)out0)[(size_t)row * 2048 + gn] = f2b(vv);
        } else if constexpr (EPI == 1) {
          float g = 1.f / (1.f + __expf(-vv));
          int t = row & (SEQ - 1), b = row >> 12;   // token row = b*SEQ + t
          ((unsigned short*)out0)[(size_t)(t * NB + b) * DIM + gn] = f2b(g);
          float iv = b2f(aux[(size_t)row * 2048 + gn]);
          out1[(size_t)row * 2048 + 1024 + gn] = f2b((1.f - g) * iv);
        } else if constexpr (EPI == 2) {
          int t = row & (SEQ - 1), b = row >> 12;
          ((float*)out0)[(size_t)(t * NB + b) * DIM + gn] = vv;
        } else {                                    // row = t*8 + b
          int b = row & 7, t = row >> 3;
          ((float*)out0)[(size_t)(b * SEQ + t) * DIM + gn] = vv;
        }
      }
    }
  }
}

// ---------------------------------------------------------------- scan
// 16 WGs x 256 thr = 64 waves; wave gw owns e-rows [16*gw, 16*gw+16).
// Per step: [wave0: 2-deep pipelined poll of 16 WG-flags (1 line, sc0 sc1)
// -> LDS release -> drain leftover | others: LDS spin] -> issue next-step
// v/g prefetch (asm, oldest ops) -> 32x dwordx4 sc0 sc1 m-loads (LLC hits),
// staged vmcnt (28-4c) -> 32 MFMAs -> tanh epi (carried v/g) -> sb store +
// m ATOMIC-SWAP (LLC-resident, ack at LLC) -> vmcnt(0) -> s_barrier ->
// tid0 flag ATOMIC-SWAP.
__global__ __launch_bounds__(256, 1)
void scan_kernel(const unsigned short* __restrict__ Ab,     // [1024][1024] bf16
                 const unsigned short* __restrict__ gscan,  // [t*8+b][1024] bf16
                 const float* __restrict__ vflat,           // [t*8+b][1024] f32
                 unsigned short* __restrict__ sb,           // [t*8+b][1024] bf16
                 unsigned short* __restrict__ mbuf,         // [2][8][1024] bf16
                 unsigned int* __restrict__ flags) {        // [16] per-WG
  const int tid  = threadIdx.x;
  const int lane = tid & 63;
  const int wave = tid >> 6;
  const int gw   = blockIdx.x * 4 + wave;    // 0..63
  const int e0   = gw * 16;
  const int q    = lane >> 4;
  const int ln   = lane & 15;
  const int bcl  = ln & 7;                   // clamped batch (n>=8 unused cols)
  const bool active = (ln < 8);
  const int eb = e0 + q * 4;

  __shared__ volatile int sready;
  if (tid == 0) sready = 0;                  // t=0 passes without a poll
  __syncthreads();

  short8 af[32];                             // A rows in registers
  #pragma unroll
  for (int ks = 0; ks < 32; ks++)
    af[ks] = *(const short8*)(Ab + (size_t)(e0 + ln) * 1024 + ks * 32 + q * 8);

  const unsigned int* fpoll = flags + (lane & 15);   // 16 flags, one line
  unsigned int* const myflag = flags + blockIdx.x;
  const float4v fz = {0.f, 0.f, 0.f, 0.f};

  // prologue: prefetch v_0 and g_1 (consumed at t=0)
  float4v vv = fz;
  ushort4v g4 = {0, 0, 0, 0};
  if (active) {
    vv = *(const float4v*)(vflat + (size_t)bcl * DIM + eb);
    g4 = *(const ushort4v*)(gscan + (size_t)(NB + bcl) * DIM + eb);
  }

  for (int t = 0; t < SEQ; t++) {
    // ---- sync: wave0 polls globally (2-deep pipeline), releases via LDS
    if (wave == 0) {
      const unsigned int target = (unsigned int)t;
      unsigned int p0, p1;
      asm volatile("global_load_dword %0, %1, off sc0 sc1"
                   : "=&v"(p0) : "v"(fpoll) : "memory");
      asm volatile("global_load_dword %0, %1, off sc0 sc1"
                   : "=&v"(p1) : "v"(fpoll) : "memory");
      for (;;) {
        asm volatile("s_waitcnt vmcnt(1)" : "+v"(p0) :: "memory");
        if (__all((int)(p0 >= target))) break;
        asm volatile("global_load_dword %0, %1, off sc0 sc1"
                     : "=&v"(p0) : "v"(fpoll) : "memory");
        asm volatile("s_waitcnt vmcnt(1)" : "+v"(p1) :: "memory");
        if (__all((int)(p1 >= target))) break;
        asm volatile("global_load_dword %0, %1, off sc0 sc1"
                     : "=&v"(p1) : "v"(fpoll) : "memory");
      }
      sready = t;                            // release siblings FIRST
      asm volatile("s_waitcnt vmcnt(0)" ::: "memory");  // drain leftover poll
    } else {
      while (sready < t) { }                 // LDS spin (local)
    }

    // ---- prefetch NEXT step's v/g (plain cached, oldest ops this step)
    const int tn = (t + 1 < SEQ) ? t + 1 : SEQ - 1;
    const int tg = (t + 2 < SEQ) ? t + 2 : SEQ - 1;
    const float* vp = vflat + (size_t)(tn * NB + bcl) * DIM + eb;
    const unsigned short* gp = gscan + (size_t)(tg * NB + bcl) * DIM + eb;
    float4v vv_n;
    ushort4v g4_n;
    asm volatile("global_load_dwordx4 %0, %1, off" : "=v"(vv_n) : "v"(vp));
    asm volatile("global_load_dwordx2 %0, %1, off" : "=v"(g4_n) : "v"(gp));

    // ---- load m_t fragments from the LLC (sc0 sc1, now LLC hits)
    const unsigned short* mb = mbuf + (size_t)(t & 1) * (NB * DIM);
    const unsigned short* mbp = mb + bcl * DIM + q * 8;
    short8 fr[32];
    #pragma unroll
    for (int ks = 0; ks < 32; ks++)
      asm volatile("global_load_dwordx4 %0, %1, off offset:%2 sc0 sc1"
                   : "=v"(fr[ks]) : "v"(mbp), "n"(ks * 64));

    float4v a0 = fz, a1 = fz, a2 = fz, a3 = fz;
    #pragma unroll
    for (int c = 0; c < 8; c++) {
      asm volatile("s_waitcnt vmcnt(%4)"
                   : "+v"(fr[4 * c]), "+v"(fr[4 * c + 1]),
                     "+v"(fr[4 * c + 2]), "+v"(fr[4 * c + 3])
                   : "n"(28 - 4 * c));
      a0 = __builtin_amdgcn_mfma_f32_16x16x32_bf16(af[4 * c + 0], fr[4 * c + 0], a0, 0, 0, 0);
      a1 = __builtin_amdgcn_mfma_f32_16x16x32_bf16(af[4 * c + 1], fr[4 * c + 1], a1, 0, 0, 0);
      a2 = __builtin_amdgcn_mfma_f32_16x16x32_bf16(af[4 * c + 2], fr[4 * c + 2], a2, 0, 0, 0);
      a3 = __builtin_amdgcn_mfma_f32_16x16x32_bf16(af[4 * c + 3], fr[4 * c + 3], a3, 0, 0, 0);
    }

    if (active) {
      size_t rowoff = (size_t)(t * NB + bcl) * DIM + eb;
      float sv[4];
      #pragma unroll
      for (int r = 0; r < 4; r++) {
        float xx = a0[r] + a1[r] + a2[r] + a3[r] + vv[r];
        float ex = __expf(-2.f * fabsf(xx));
        float th = (1.f - ex) / (1.f + ex);
        sv[r] = copysignf(th, xx);
      }
      ushort4v sp;
      #pragma unroll
      for (int r = 0; r < 4; r++) sp[r] = f2b(sv[r]);
      *(ushort4v*)(sb + rowoff) = sp;                       // state for out-proj
      if (t < SEQ - 1) {                                    // m_{t+1} = g*s
        unsigned long long mv =
            (unsigned long long)((unsigned int)f2b(b2f(g4[0]) * sv[0]) |
                                 ((unsigned int)f2b(b2f(g4[1]) * sv[1]) << 16)) |
            ((unsigned long long)((unsigned int)f2b(b2f(g4[2]) * sv[2]) |
                                  ((unsigned int)f2b(b2f(g4[3]) * sv[3]) << 16)) << 32);
        unsigned short* mn = mbuf + (size_t)((t + 1) & 1) * (NB * DIM) + bcl * DIM + eb;
        // ATOMIC transport: executes at the LLC, line stays resident there.
        asm volatile("global_atomic_swap_x2 %0, %1, off"
                     :: "v"(mn), "v"(mv) : "memory");
      }
    }

    vv = vv_n;                               // carry next step's operands
    g4 = g4_n;

    if (t == SEQ - 1) break;

    // publish: ack m-atomics at the LLC, WG barrier, one flag atomic
    asm volatile("s_waitcnt vmcnt(0)" ::: "memory");
    __builtin_amdgcn_s_barrier();
    if (tid == 0) {
      unsigned int fv = (unsigned int)(t + 1);
      asm volatile("global_atomic_swap %0, %1, off"
                   :: "v"(myflag), "v"(fv) : "memory");
    }
  }
}

// ---------------------------------------------------------------- launch
extern "C" void kernel_launch(void* const* d_in, const int* in_sizes, int n_in,
                              void* d_out, int out_size, void* d_ws, size_t ws_size,
                              hipStream_t stream) {
  const float* x      = (const float*)d_in[0];
  const float* A      = (const float*)d_in[1];
  const float* Bm     = (const float*)d_in[2];
  const float* W_in   = (const float*)d_in[3];
  const float* b_in   = (const float*)d_in[4];
  const float* W_gate = (const float*)d_in[5];
  const float* b_gate = (const float*)d_in[6];
  const float* W_out  = (const float*)d_in[7];
  const float* b_out  = (const float*)d_in[8];

  char* ws = (char*)d_ws;
  // workspace layout (~281 MB total)
  unsigned short* xb      = (unsigned short*)(ws);                 // 64 MB (reused as sb)
  unsigned short* inpq    = (unsigned short*)(ws + 67108864);      // 128 MB [n][2048]
  unsigned short* gscan   = (unsigned short*)(ws + 201326592);     // 64 MB
  unsigned short* Wb_in   = (unsigned short*)(ws + 268435456);     // 2 MB
  unsigned short* Wb_gate = (unsigned short*)(ws + 270532608);     // 2 MB
  unsigned short* Wb_out  = (unsigned short*)(ws + 272629760);     // 2 MB
  unsigned short* Wcat    = (unsigned short*)(ws + 274726912);     // 4 MB [e][2048]
  unsigned short* Ab      = (unsigned short*)(ws + 278921216);     // 2 MB
  unsigned short* mbuf    = (unsigned short*)(ws + 281018368);     // 32 KB (2x8x1024)
  unsigned int*   flags   = (unsigned int*)(ws + 281051136);       // 64 B (16 WG flags)
  float*          vflat   = (float*)d_out;          // v lives in d_out pre-scan
  unsigned short* sbuf    = xb;                     // states overwrite xb

  // prep
  cast_bf16<<<(33554432 / 4 + 255) / 256, 256, 0, stream>>>(x, xb, 33554432);
  cast_bf16<<<1024, 256, 0, stream>>>(W_in,   Wb_in,   1048576);
  cast_bf16<<<1024, 256, 0, stream>>>(W_gate, Wb_gate, 1048576);
  cast_bf16<<<1024, 256, 0, stream>>>(W_out,  Wb_out,  1048576);
  build_wcat<<<1024, 256, 0, stream>>>(Bm, A, Wcat, Ab);
  // zero mbuf (8192 u32) + 16 WG flags
  zero_u32<<<(8208 + 255) / 256, 256, 0, stream>>>((unsigned int*)mbuf, 8208);

  dim3 grid(NTOK / 128, DIM / 128);
  // inp = x @ W_in^T + b_in
  gemm_nt<0><<<grid, 256, 0, stream>>>(xb, DIM, Wb_in, DIM, DIM, b_in,
                                       (void*)inpq, nullptr, nullptr);
  // g = sigmoid(inp @ W_gate^T + b_gate); q = (1-g)*inp
  gemm_nt<1><<<grid, 256, 0, stream>>>(inpq, 2048, Wb_gate, DIM, DIM, b_gate,
                                       (void*)gscan, inpq, inpq);
  // v = [inp, q] @ [B; A]^T   (K = 2048)
  gemm_nt<2><<<grid, 256, 0, stream>>>(inpq, 2048, Wcat, 2048, 2048, b_in,
                                       (void*)vflat, nullptr, nullptr);
  // sequential scan
  scan_kernel<<<16, 256, 0, stream>>>(Ab, gscan, vflat, sbuf, mbuf, flags);
  // out = states @ W_out^T + b_out  (with [t*8+b] -> [b*4096+t] permute)
  gemm_nt<3><<<grid, 256, 0, stream>>>(sbuf, DIM, Wb_out, DIM, DIM, b_out,
                                       (void*)d_out, nullptr, nullptr);
}